// Round 3
// baseline (143.837 us; speedup 1.0000x reference)
//
#include <hip/hip_runtime.h>
#include <math.h>

// InterfaceBoundaryLoss — B=4, H=W=2048, DX=DY=0.01, E_IN=2, CONST=1, WEIGHT=1.
//
// Round 2 restructure: single compute kernel + 4-byte memset.
//  * boundary count nb is a deterministic function of geometry → computed
//    exactly on the HOST (integer loop) in kernel_launch; no global count
//    reduction needed on device.
//  * Each block: per-wave f64 shuffle reduce → LDS combine → ONE
//    atomicAdd(float) of S_block/(4·nb) into d_out. d_out zeroed by a
//    graph-capturable hipMemsetAsync (harness re-poisons it to 0xAA before
//    timed replays, so we must zero it ourselves).
//  * Annulus enumeration per (row, side) wave as in round 1:
//    boundary ⟺ dx² ∈ [261122−dy², 263168−dy²]; ≤45 contiguous columns per
//    side → coalesced. interface ⟺ d²<512²; ¬a==¬b ⟺ a==b so both
//    subdomains share FD-direction selects. No edge clamps needed.

#define Ww 2048
#define Bn 4
#define HW (2048 * 2048)
#define NROWS 1025           // dy = -512..512
#define NWAVES (NROWS * 2)   // (row, side)
#define BLOCK 256
#define WPB (BLOCK / 64)
#define NBLK ((NWAVES + WPB - 1) / WPB)

__device__ __forceinline__ bool intf(int dy, int dx) {
    return (dy * dy + dx * dx) < 262144;   // 512^2
}

__device__ __forceinline__ double waveReduce(double v) {
#pragma unroll
    for (int off = 32; off > 0; off >>= 1)
        v += __shfl_down(v, off, 64);
    return v;
}

__global__ __launch_bounds__(BLOCK) void fusedLoss(
    const float* __restrict__ s1, const float* __restrict__ s2,
    float* __restrict__ out, double invDenom)
{
    const int lane = threadIdx.x & 63;
    const int w = blockIdx.x * WPB + (threadIdx.x >> 6);

    double lsum = 0.0;

    if (w < NWAVES) {
        const int side = w & 1;            // 0: dx >= 0, 1: dx < 0
        const int dy = (w >> 1) - 512;     // -512..512
        const int dy2 = dy * dy;
        const int a = 263168 - dy2;        // dx^2 <= a
        const int b = 261122 - dy2;        // dx^2 >= b

        int xhi = (int)sqrt((double)a);
        while ((xhi + 1) * (xhi + 1) <= a) ++xhi;
        while (xhi * xhi > a) --xhi;
        int xlo = 0;
        if (b > 0) {
            xlo = (int)sqrt((double)b);
            while (xlo * xlo < b) ++xlo;
            while (xlo > 0 && (xlo - 1) * (xlo - 1) >= b) --xlo;
        }
        if (side == 1 && xlo < 1) xlo = 1;   // dx=0 owned by side 0

        const int x = xlo + lane;
        if (x <= xhi) {
            const int dx = side ? -x : x;
            const int i = 1024 + dy, j = 1024 + dx;

            const bool mc = intf(dy, dx);
            const bool eqx_up = (mc == intf(dy - 1, dx));
            const bool eqx_dn = (mc == intf(dy + 1, dx));
            const bool eqy_lf = (mc == intf(dy, dx - 1));
            const bool eqy_rt = (mc == intf(dy, dx + 1));

            const int base = i * Ww + j;
#pragma unroll
            for (int bb = 0; bb < Bn; ++bb) {
                const float* p1 = s1 + (size_t)bb * HW;
                const float* p2 = s2 + (size_t)bb * HW;
                const float c1 = p1[base];
                const float c2 = p2[base];
                const float d = c1 - c2;
                lsum += (double)(d * d);

                float gx1 = 0.f, gx2 = 0.f, gy1 = 0.f, gy2 = 0.f;
                if (eqx_up) {
                    gx1 = (c1 - p1[base - Ww]) / 0.01f;
                    gx2 = (c2 - p2[base - Ww]) / 0.01f;
                } else if (eqx_dn) {
                    gx1 = (c1 - p1[base + Ww]) / 0.01f;
                    gx2 = (c2 - p2[base + Ww]) / 0.01f;
                }
                if (eqy_lf) {
                    gy1 = (c1 - p1[base - 1]) / 0.01f;
                    gy2 = (c2 - p2[base - 1]) / 0.01f;
                } else if (eqy_rt) {
                    gy1 = (c1 - p1[base + 1]) / 0.01f;
                    gy2 = (c2 - p2[base + 1]) / 0.01f;
                }
                float t;
                t = 2.0f * gx1 - 1.0f; lsum += (double)(t * t);
                t = 2.0f * gy1 - 1.0f; lsum += (double)(t * t);
                t = 2.0f * gx2 - 1.0f; lsum += (double)(t * t);
                t = 2.0f * gy2 - 1.0f; lsum += (double)(t * t);
            }
        }
    }

    const double wsum = waveReduce(lsum);
    __shared__ double ssum[WPB];
    const int wave = threadIdx.x >> 6;
    if (lane == 0) ssum[wave] = wsum;
    __syncthreads();
    if (threadIdx.x == 0) {
        double S = 0.0;
#pragma unroll
        for (int k = 0; k < WPB; ++k) S += ssum[k];
        atomicAdd(out, (float)(S * invDenom));
    }
}

extern "C" void kernel_launch(void* const* d_in, const int* in_sizes, int n_in,
                              void* d_out, int out_size, void* d_ws, size_t ws_size,
                              hipStream_t stream) {
    const float* s1 = (const float*)d_in[0];
    const float* s2 = (const float*)d_in[1];
    float* out = (float*)d_out;

    // Host-side exact boundary count (deterministic geometry; same every call).
    long long nb = 0;
    for (int dy = -512; dy <= 512; ++dy) {
        const int dy2 = dy * dy;
        const int a = 263168 - dy2;        // dx^2 <= a
        const int b = 261122 - dy2;        // dx^2 >= b
        if (a < 0) continue;
        int xhi = (int)sqrt((double)a);
        while ((xhi + 1) * (xhi + 1) <= a) ++xhi;
        while (xhi > 0 && xhi * xhi > a) --xhi;
        int xlo = 0;
        if (b > 0) {
            xlo = (int)sqrt((double)b);
            while (xlo * xlo < b) ++xlo;
            while (xlo > 0 && (xlo - 1) * (xlo - 1) >= b) --xlo;
        }
        if (xhi < xlo) continue;
        nb += (xlo == 0) ? (2LL * xhi + 1) : 2LL * (xhi - xlo + 1);
    }
    const double invDenom = 1.0 / (4.0 * (double)nb);   // loss = S/(B·nb)

    hipMemsetAsync(out, 0, sizeof(float), stream);
    fusedLoss<<<NBLK, BLOCK, 0, stream>>>(s1, s2, out, invDenom);
}